// Round 4
// baseline (181.822 us; speedup 1.0000x reference)
//
#include <hip/hip_runtime.h>

namespace {
constexpr int CC    = 10;                  // cluster gap window C
constexpr int TT    = 500;                 // time steps
constexpr int NN    = 128;                 // neurons per batch row
constexpr int G     = 10;                  // temporal segments per trace
constexpr int LSEG  = TT / G;              // 50 core steps
constexpr int HALO  = CC;                  // 10
constexpr int NB    = 32;                  // neurons per block
constexpr int NELEM = LSEG + 2 * HALO;     // 70 column values per thread
constexpr int MAXG  = TT / (CC + 1) + 1;   // 46 max global clusters
}

// ---- single fused kernel: 10 in-block temporal segments + merge; full register preload ----
// grid = 4 neuron-quarters x 256 batches = 1024 blocks of 320 thr.
// launch_bounds (320,4): 128-VGPR budget -> room for the 70-reg preload, no spill.
__global__ __launch_bounds__(320, 4)
void fused_kernel(const float* __restrict__ vmem, const int* __restrict__ labels,
                  float* __restrict__ out) {
    const int tid = threadIdx.x;           // 0..319
    const int g   = tid >> 5;              // segment 0..9
    const int ln  = tid & 31;              // local neuron
    const int b   = blockIdx.y;            // batch
    const int n   = (blockIdx.x << 5) | ln;// global neuron 0..127
    const int a   = g * LSEG;
    const bool firstSeg = (g == 0), lastSeg = (g == G - 1);
    const float* __restrict__ col = vmem + (size_t)b * TT * NN + n;

    __shared__ float s_rec[G][10][NB];     // 12.8 KB: per-segment records
    __shared__ float s_gl[MAXG][NB];       // 5.9 KB: global cluster list
    __shared__ float wb[512];              // pass-2 column staging (half-wave)

    // ---- preload all 70 values to registers (i covers ofs = i-10 in [-10, 60)) ----
    // Clamp only where any segment can need it (i<10: t<0 at g=0; i>=60: t>499 at g=9).
    // Uniform code path: per-i clamp folds to one VALU op or nothing.
    float r[NELEM];
    #pragma unroll
    for (int i = 0; i < NELEM; ++i) {
        int t = a + i - HALO;
        if (i < HALO)          t = t < 0 ? 0 : t;
        if (i >= LSEG + HALO)  t = t > TT - 1 ? TT - 1 : t;
        r[i] = col[t * NN];
    }
    __builtin_amdgcn_sched_barrier(0);     // loads may NOT sink into the scan

    int   ls = -(1 << 20), lcount = 0, hdne = 0, tmn = 0, hasu = 0;
    float ccm = -1e30f, rmax = -1e30f, hdm = -1e30f, vmx = -1e30f, m0 = -1e30f;

    #pragma unroll
    for (int i = 0; i < NELEM; ++i) {
        const int ofs = i - HALO;                      // compile-time
        const int t   = a + ofs;
        float v = r[i];
        if ((ofs < 0 && firstSeg) || (ofs >= LSEG && lastSeg)) v = -1.0f;
        const bool spike = v >= 0.0f;
        if (ofs >= 0 && ofs < LSEG) {                  // core accounting
            const float rm2 = fmaxf(rmax, v);
            if (spike) {
                if (t - ls > CC) {                     // halo gives full C history
                    if (lcount > 0) s_rec[g][lcount - 1][ln] = ccm;
                    ccm = v; ++lcount;
                } else if (lcount == 0) { hdne = 1; hdm = fmaxf(hdm, rm2); }
                else ccm = fmaxf(ccm, rm2);
                rmax = -1e30f;
            } else rmax = rm2;
            if (v > vmx) { vmx = v; tmn = t; }         // strict >: first argmax
        }
        if (spike) ls = t;                             // halo/tail spikes feed ls
        if (ofs >= HALO) {                             // eval u = t-10 in core
            const float vu = r[i - 10];                // raw v[t-10]
            if (ls < t - 2 * CC) { hasu = 1; if (vu > m0) m0 = vu; }
        }
    }
    if (lcount > 0) s_rec[g][lcount - 1][ln] = ccm;    // close final cluster

    s_rec[g][5][ln] = __int_as_float(lcount | (hdne << 3) | (hasu << 4) | (tmn << 5));
    s_rec[g][6][ln] = hdm;     // head-piece max
    s_rec[g][7][ln] = rmax;    // tail gap max (since last core spike)
    s_rec[g][8][ln] = vmx;
    s_rec[g][9][ln] = m0;
    __syncthreads();

    // ---------------- merge + loss: half-wave, one thread per neuron ----------------
    if (tid < NB) {
        int gi = 0, g_nc = 0, g_hasu = 0, g_tm = 0;
        bool open = false; float cur = -1e30f, ptg = -1e30f;
        float g_vmax = -1e30f, g_m0 = -1e30f;
        #pragma unroll
        for (int s2 = 0; s2 < G; ++s2) {
            const int pk = __float_as_int(s_rec[s2][5][tid]);
            const int k = pk & 7, hne = (pk >> 3) & 1;
            g_nc += k; g_hasu |= (pk >> 4) & 1;
            const float vmS = s_rec[s2][8][tid];
            if (vmS > g_vmax) { g_vmax = vmS; g_tm = pk >> 5; }   // seg order = t order
            const float m0S = s_rec[s2][9][tid];
            if (m0S > g_m0) g_m0 = m0S;
            if (open) {
                if (hne) { cur = fmaxf(cur, fmaxf(ptg, s_rec[s2][6][tid]));
                           ptg = s_rec[s2][7][tid]; }
                if (k > 0 || !hne) { s_gl[gi][tid] = cur; ++gi; open = false; }
            }
            if (k > 0) {
                for (int i = 0; i < k - 1; ++i) { s_gl[gi][tid] = s_rec[s2][i][tid]; ++gi; }
                cur = s_rec[s2][k - 1][tid]; open = true; ptg = s_rec[s2][7][tid];
            }
        }
        if (open) { s_gl[gi][tid] = cur; ++gi; }       // gi == g_nc

        const int label = labels[b * NN + n];

        // pass-2 m_rest: half-wave cooperative, rare (needs 21-step spike-free window)
        const bool need2 = (label > g_nc) && g_hasu && (label - g_nc >= 2);
        float mrest = g_vmax;                          // full2 surrogate default
        unsigned long long bal = __ballot(need2);      // inactive lanes contribute 0
        const float* colbase = vmem + (size_t)b * TT * NN;
        while (bal) {
            const int fl = __ffsll(bal) - 1;
            bal &= bal - 1;
            const int   nf    = (blockIdx.x << 5) | fl;    // flagged global neuron
            const int   tmf   = __shfl(g_tm, fl);
            const float vmaxf = __shfl(g_vmax, fl);
            #pragma unroll
            for (int j = 0; j < 16; ++j) {             // stage column: 16 loads/lane
                const int t = tid * 16 + j;
                wb[t] = (t < TT) ? colbase[(size_t)t * NN + nf] : -1.0f;
            }
            asm volatile("s_waitcnt lgkmcnt(0)" ::: "memory");  // wave-lockstep LDS
            __builtin_amdgcn_wave_barrier();
            int ls2 = -1000, lh = 0; float lm = -1e30f;
            const int u0 = tid * 16;
            for (int t2 = u0 - 10; t2 < u0 + 26; ++t2) {
                const float v = (t2 >= 0 && t2 < 512) ? wb[t2] : -1.0f;
                if (v >= 0.0f) ls2 = t2;
                const int u = t2 - 10;
                if (u >= u0 && u < u0 + 16 && u < TT) {
                    if (ls2 < u - 10 && (u < tmf - CC / 2 || u > tmf + CC / 2)) {
                        lh = 1; const float vu = wb[u]; if (vu > lm) lm = vu;
                    }
                }
            }
            #pragma unroll
            for (int off = 16; off > 0; off >>= 1) {   // 32-lane reduce; lane-0 tree clean
                lm = fmaxf(lm, __shfl_down(lm, off));
                lh |= __shfl_down(lh, off);
            }
            const float res = __shfl(lh ? lm : vmaxf, 0);
            if (tid == fl) mrest = res;
            __builtin_amdgcn_wave_barrier();
        }

        // branch select
        float contrib = 0.0f;
        if (label > g_nc) {
            if (!g_hasu) contrib = g_vmax;             // full0 -> vmax
            else {
                const float dE = (float)(label - g_nc);        // >= 1
                contrib = -((g_m0 + (dE - 1.0f) * mrest) / dE);
            }
        } else if (label < g_nc) {
            const int kk = g_nc - label;               // 1..nc
            float ssum = 0.0f;
            for (int i = 0; i < kk; ++i) {             // sum kk smallest cluster maxes
                float mn = 1e30f; int mj = 0;
                for (int jj = 0; jj < g_nc; ++jj) {
                    const float x = s_gl[jj][tid];
                    if (x < mn) { mn = x; mj = jj; }
                }
                ssum += mn; s_gl[mj][tid] = 1e30f;
            }
            contrib = ssum / (float)kk;
        }

        out[1 + b * NN + n] = (float)g_nc;             // spike_output

        float w = contrib;                             // 32-lane reduce -> 1 atomic/block
        #pragma unroll
        for (int off = 16; off > 0; off >>= 1) w += __shfl_down(w, off);
        if (tid == 0) atomicAdd(out, w);
    }
}

extern "C" void kernel_launch(void* const* d_in, const int* in_sizes, int n_in,
                              void* d_out, int out_size, void* d_ws, size_t ws_size,
                              hipStream_t stream) {
    const float* vmem   = (const float*)d_in[0];
    // d_in[1] (vlastmem) and d_in[3] (ratio) are unused by the reference forward.
    const int*   labels = (const int*)d_in[2];
    float*       out    = (float*)d_out;
    (void)d_ws; (void)ws_size;                         // workspace deliberately untouched

    const int B = in_sizes[2] / NN;                    // 256

    hipMemsetAsync(out, 0, sizeof(float), stream);     // zero the loss accumulator
    hipLaunchKernelGGL(fused_kernel, dim3(NN / NB, B), dim3(G * NB), 0, stream,
                       vmem, labels, out);
}

// Round 5
// 160.781 us; speedup vs baseline: 1.1309x; 1.1309x over previous
//
#include <hip/hip_runtime.h>

namespace {
constexpr int CC    = 10;                  // cluster gap window C
constexpr int TT    = 500;                 // time steps
constexpr int NN    = 128;                 // neurons per batch row
constexpr int G     = 10;                  // temporal segments per trace
constexpr int LSEG  = TT / G;              // 50 core steps
constexpr int HALO  = CC;                  // 10
constexpr int NB    = 64;                  // neurons per block (one wave's lanes)
constexpr int NELEM = LSEG + 2 * HALO;     // 70 column values per thread
constexpr int MAXG  = TT / (CC + 1) + 1;   // 46 max global clusters
}

// ---- fused kernel, wave-aligned: block = 10 waves x 64 lanes; wave w = segment w ----
// Every load: 64 lanes x consecutive n = one 256 B transaction.
// launch_bounds(640,2) is NON-binding (1 block/CU guaranteed, VGPR cap 256): the 70-reg
// preload must not be clamped/spilled (R3/R4 lesson: binding bounds + 5-wave blocks spill).
__global__ __launch_bounds__(640, 2)
void fused_kernel(const float* __restrict__ vmem, const int* __restrict__ labels,
                  float* __restrict__ out) {
    const int tid = threadIdx.x;           // 0..639
    const int g   = tid >> 6;              // segment 0..9 == wave id
    const int ln  = tid & 63;              // lane == local neuron
    const int b   = blockIdx.y;            // batch
    const int n   = (blockIdx.x << 6) | ln;// global neuron 0..127
    const int a   = g * LSEG;
    const bool firstSeg = (g == 0), lastSeg = (g == G - 1);
    const float* __restrict__ col = vmem + (size_t)b * TT * NN + n;

    __shared__ float s_rec[G][10][NB];     // 25.6 KB: per-segment records
    __shared__ float s_gl[MAXG][NB];       // 11.5 KB: global cluster list
    __shared__ float wb[512];              // 2 KB: pass-2 column staging (wave 0)

    // ---- preload all 70 values to registers (i covers ofs = i-10 in [-10, 60)) ----
    float r[NELEM];
    #pragma unroll
    for (int i = 0; i < NELEM; ++i) {
        int t = a + i - HALO;
        if (i < HALO)          t = t < 0 ? 0 : t;      // only g=0 ever clamps low
        if (i >= LSEG + HALO)  t = t > TT - 1 ? TT - 1 : t;   // only g=9 clamps high
        r[i] = col[t * NN];
    }
    __builtin_amdgcn_sched_barrier(0);     // loads may NOT sink into the scan

    int   ls = -(1 << 20), lcount = 0, hdne = 0, tmn = 0, hasu = 0;
    float ccm = -1e30f, rmax = -1e30f, hdm = -1e30f, vmx = -1e30f, m0 = -1e30f;

    #pragma unroll
    for (int i = 0; i < NELEM; ++i) {
        const int ofs = i - HALO;                      // compile-time
        const int t   = a + ofs;
        float v = r[i];
        if ((ofs < 0 && firstSeg) || (ofs >= LSEG && lastSeg)) v = -1.0f;
        const bool spike = v >= 0.0f;
        if (ofs >= 0 && ofs < LSEG) {                  // core accounting
            const float rm2 = fmaxf(rmax, v);
            if (spike) {
                if (t - ls > CC) {                     // halo gives full C history
                    if (lcount > 0) s_rec[g][lcount - 1][ln] = ccm;
                    ccm = v; ++lcount;
                } else if (lcount == 0) { hdne = 1; hdm = fmaxf(hdm, rm2); }
                else ccm = fmaxf(ccm, rm2);
                rmax = -1e30f;
            } else rmax = rm2;
            if (v > vmx) { vmx = v; tmn = t; }         // strict >: first argmax
        }
        if (spike) ls = t;                             // halo/tail spikes feed ls
        if (ofs >= HALO) {                             // eval u = t-10 in core
            const float vu = r[i - 10];                // raw v[t-10]
            if (ls < t - 2 * CC) { hasu = 1; if (vu > m0) m0 = vu; }
        }
    }
    if (lcount > 0) s_rec[g][lcount - 1][ln] = ccm;    // close final cluster

    s_rec[g][5][ln] = __int_as_float(lcount | (hdne << 3) | (hasu << 4) | (tmn << 5));
    s_rec[g][6][ln] = hdm;     // head-piece max
    s_rec[g][7][ln] = rmax;    // tail gap max (since last core spike)
    s_rec[g][8][ln] = vmx;
    s_rec[g][9][ln] = m0;
    __syncthreads();

    // ---------------- merge + loss: wave 0, one lane per neuron ----------------
    if (tid < NB) {
        int gi = 0, g_nc = 0, g_hasu = 0, g_tm = 0;
        bool open = false; float cur = -1e30f, ptg = -1e30f;
        float g_vmax = -1e30f, g_m0 = -1e30f;
        #pragma unroll
        for (int s2 = 0; s2 < G; ++s2) {
            const int pk = __float_as_int(s_rec[s2][5][tid]);
            const int k = pk & 7, hne = (pk >> 3) & 1;
            g_nc += k; g_hasu |= (pk >> 4) & 1;
            const float vmS = s_rec[s2][8][tid];
            if (vmS > g_vmax) { g_vmax = vmS; g_tm = pk >> 5; }   // seg order = t order
            const float m0S = s_rec[s2][9][tid];
            if (m0S > g_m0) g_m0 = m0S;
            if (open) {
                if (hne) { cur = fmaxf(cur, fmaxf(ptg, s_rec[s2][6][tid]));
                           ptg = s_rec[s2][7][tid]; }
                if (k > 0 || !hne) { s_gl[gi][tid] = cur; ++gi; open = false; }
            }
            if (k > 0) {
                for (int i = 0; i < k - 1; ++i) { s_gl[gi][tid] = s_rec[s2][i][tid]; ++gi; }
                cur = s_rec[s2][k - 1][tid]; open = true; ptg = s_rec[s2][7][tid];
            }
        }
        if (open) { s_gl[gi][tid] = cur; ++gi; }       // gi == g_nc

        const int label = labels[b * NN + n];

        // pass-2 m_rest: full-wave cooperative, rare (needs 21-step spike-free window)
        const bool need2 = (label > g_nc) && g_hasu && (label - g_nc >= 2);
        float mrest = g_vmax;                          // full2 surrogate default
        unsigned long long bal = __ballot(need2);
        const float* colbase = vmem + (size_t)b * TT * NN;
        while (bal) {
            const int fl = __ffsll(bal) - 1;
            bal &= bal - 1;
            const int   nf    = (blockIdx.x << 6) | fl;    // flagged global neuron
            const int   tmf   = __shfl(g_tm, fl);
            const float vmaxf = __shfl(g_vmax, fl);
            #pragma unroll
            for (int j = 0; j < 8; ++j) {              // stage column: 8 loads/lane
                const int t = tid * 8 + j;
                wb[t] = (t < TT) ? colbase[(size_t)t * NN + nf] : -1.0f;
            }
            asm volatile("s_waitcnt lgkmcnt(0)" ::: "memory");  // wave-lockstep LDS
            __builtin_amdgcn_wave_barrier();
            int ls2 = -1000, lh = 0; float lm = -1e30f;
            const int u0 = tid * 8;
            for (int t2 = u0 - 10; t2 < u0 + 18; ++t2) {
                const float v = (t2 >= 0 && t2 < 512) ? wb[t2] : -1.0f;
                if (v >= 0.0f) ls2 = t2;
                const int u = t2 - 10;
                if (u >= u0 && u < u0 + 8 && u < TT) {
                    if (ls2 < u - 10 && (u < tmf - CC / 2 || u > tmf + CC / 2)) {
                        lh = 1; const float vu = wb[u]; if (vu > lm) lm = vu;
                    }
                }
            }
            #pragma unroll
            for (int off = 32; off > 0; off >>= 1) {   // 64-lane wave reduce
                lm = fmaxf(lm, __shfl_down(lm, off));
                lh |= __shfl_down(lh, off);
            }
            const float res = __shfl(lh ? lm : vmaxf, 0);
            if (tid == fl) mrest = res;
            __builtin_amdgcn_wave_barrier();
        }

        // branch select
        float contrib = 0.0f;
        if (label > g_nc) {
            if (!g_hasu) contrib = g_vmax;             // full0 -> vmax
            else {
                const float dE = (float)(label - g_nc);        // >= 1
                contrib = -((g_m0 + (dE - 1.0f) * mrest) / dE);
            }
        } else if (label < g_nc) {
            const int kk = g_nc - label;               // 1..nc
            float ssum = 0.0f;
            for (int i = 0; i < kk; ++i) {             // sum kk smallest cluster maxes
                float mn = 1e30f; int mj = 0;
                for (int jj = 0; jj < g_nc; ++jj) {
                    const float x = s_gl[jj][tid];
                    if (x < mn) { mn = x; mj = jj; }
                }
                ssum += mn; s_gl[mj][tid] = 1e30f;
            }
            contrib = ssum / (float)kk;
        }

        out[1 + b * NN + n] = (float)g_nc;             // spike_output

        float w = contrib;                             // wave reduce -> 1 atomic/block
        #pragma unroll
        for (int off = 32; off > 0; off >>= 1) w += __shfl_down(w, off);
        if (tid == 0) atomicAdd(out, w);
    }
}

extern "C" void kernel_launch(void* const* d_in, const int* in_sizes, int n_in,
                              void* d_out, int out_size, void* d_ws, size_t ws_size,
                              hipStream_t stream) {
    const float* vmem   = (const float*)d_in[0];
    // d_in[1] (vlastmem) and d_in[3] (ratio) are unused by the reference forward.
    const int*   labels = (const int*)d_in[2];
    float*       out    = (float*)d_out;
    (void)d_ws; (void)ws_size;                         // workspace deliberately untouched

    const int B = in_sizes[2] / NN;                    // 256

    hipMemsetAsync(out, 0, sizeof(float), stream);     // zero the loss accumulator
    hipLaunchKernelGGL(fused_kernel, dim3(NN / NB, B), dim3(G * NB), 0, stream,
                       vmem, labels, out);
}